// Round 12
// baseline (216.788 us; speedup 1.0000x reference)
//
#include <hip/hip_runtime.h>
#include <hip/hip_bf16.h>

#define LL 4096
#define DM 96
#define DI 192
#define NS 16
#define RK 6
#define RKP 8              // padded stride for dt coeffs (16B alignment)
#define KD 4
#define CPROJ 38
#define NC (KD*DI*NS)      // 12288 independent chains
#define PT 32              // t-tile for k_proj
#define WS 196             // LDS row stride (4*odd -> quad-bank spread)
#define OT 16              // l-tile for k_oproj
#define L2E 1.44269504f

__device__ __forceinline__ float b2f(__hip_bfloat16 v){ return __bfloat162float(v); }

// inline dtype detect: 64 lanes sample even halfwords of x; bf16 data has sane exponents
__device__ __forceinline__ int detect_bf16(const unsigned short* __restrict__ xh, int tid, int* sflag){
  if (tid < 64){
    unsigned short u = xh[2*tid];
    int e = (u >> 7) & 0xFF;
    int sane = (e >= 107 && e <= 131) ? 1 : 0;
    unsigned long long m = __ballot(sane);
    if (tid == 0) *sflag = (__popcll(m) >= 32) ? 1 : 0;
  }
  return 0;
}

// -------- K0: convert ALL 12 tensors to fp32 in one launch (self-detecting) --------
struct P12 { const void* p[12]; };
__global__ void k_convert_all(P12 ptrs, float* __restrict__ dst) {
  const int off[13] = {0,393216,430080,431808,432000,461184,465792,466560,
                       478848,479616,479808,480000,498432};
  __shared__ int sflag;
  detect_bf16((const unsigned short*)ptrs.p[0], threadIdx.x, &sflag);
  __syncthreads();
  int f = sflag;
  int i = blockIdx.x * 256 + threadIdx.x;
  if (i >= 498432) return;
  int j = 0;
  #pragma unroll
  for (int s = 1; s < 12; s++) if (i >= off[s]) j = s;
  int e = i - off[j];
  if (f) dst[i] = b2f(((const __hip_bfloat16*)ptrs.p[j])[e]);
  else   dst[i] = ((const float*)ptrs.p[j])[e];
}

// -------- K1: in_proj GEMM --------
__global__ void k_inproj(const float* __restrict__ x,
                         const float* __restrict__ w,
                         float* __restrict__ xx, float* __restrict__ z) {
  __shared__ float xr[8*DM];
  int l0 = blockIdx.x * 8;
  int tid = threadIdx.x; // 384
  for (int i = tid; i < 8*DM; i += 384) xr[i] = x[l0*DM + i];
  __syncthreads();
  int e = tid;
  float acc[8];
  #pragma unroll
  for (int i=0;i<8;i++) acc[i]=0.f;
  const float* wr = w + e*DM;
  for (int c=0;c<DM;c++){
    float wv = wr[c];
    #pragma unroll
    for (int i=0;i<8;i++) acc[i] = fmaf(wv, xr[i*DM+c], acc[i]);
  }
  if (e < DI) {
    #pragma unroll
    for (int i=0;i<8;i++) xx[(l0+i)*DI + e] = acc[i];
  } else {
    int e2 = e - DI;
    #pragma unroll
    for (int i=0;i<8;i++) z[(l0+i)*DI + e2] = acc[i];
  }
}

// -------- K2: depthwise 3x3 conv + bias + SiLU --------
__global__ void k_conv(const float* __restrict__ xx,
                       const float* __restrict__ cw,
                       const float* __restrict__ cb,
                       float* __restrict__ xc) {
  int l = blockIdx.x;
  int d = threadIdx.x; // 192
  int h = l >> 6, w = l & 63;
  float acc = cb[d];
  #pragma unroll
  for (int ki=0; ki<3; ki++){
    int hh = h + ki - 1;
    if ((unsigned)hh >= 64u) continue;
    #pragma unroll
    for (int kj=0;kj<3;kj++){
      int wj = w + kj - 1;
      if ((unsigned)wj >= 64u) continue;
      acc = fmaf(cw[d*9 + ki*3 + kj], xx[(hh*64+wj)*DI + d], acc);
    }
  }
  xc[l*DI + d] = acc / (1.f + __expf(-acc));
}

__device__ __forceinline__ int dir_map(int k, int t){
  if (k==0) return t;
  if (k==1) return ((t&63)<<6) | (t>>6);
  if (k==2) return 4095 - t;
  int u = 4095 - t; return ((u&63)<<6) | (u>>6);
}

// -------- K3: x_dbl projection as register-tiled LDS GEMM; k==0 blocks also zero yacc --------
__global__ void __launch_bounds__(256) k_proj(const float* __restrict__ xc,
                       const float* __restrict__ xpw,
                       float* __restrict__ dts,
                       float* __restrict__ Bb, float* __restrict__ Cb,
                       float* __restrict__ yacc) {
  __shared__ float wl[CPROJ*WS];   // 29.8 KB
  __shared__ float xs[PT*WS];      // 25.1 KB
  int b = blockIdx.x;              // KD * 128
  int k = b >> 7;
  int t_base = (b & 127) * PT;
  int tid = threadIdx.x;
  if (k == 0){                     // zero yacc slice [t_base*DI, (t_base+PT)*DI)
    float4* yz = (float4*)(yacc + (size_t)t_base*DI);
    for (int idx = tid; idx < PT*DI/4; idx += 256)
      yz[idx] = make_float4(0.f,0.f,0.f,0.f);
  }
  for (int idx = tid; idx < CPROJ*DI; idx += 256){
    int cc = idx / DI, j = idx - cc*DI;
    wl[cc*WS + j] = xpw[(k*CPROJ + cc)*DI + j];
  }
  for (int idx = tid; idx < PT*DI; idx += 256){
    int tt = idx / DI, j = idx - tt*DI;
    xs[tt*WS + j] = xc[dir_map(k, t_base + tt)*DI + j];
  }
  __syncthreads();
  int tg = tid & 7;        // t-group: cols {tg, tg+8, tg+16, tg+24}
  int ty = tid >> 3;       // 0..31: rows {ty, ty+32 if <38}
  int cc0 = ty;
  int has2 = (ty + 32 < CPROJ);
  int cc1 = has2 ? (ty + 32) : ty;
  float a0x=0.f,a0y=0.f,a0z=0.f,a0w=0.f;
  float a1x=0.f,a1y=0.f,a1z=0.f,a1w=0.f;
  const float4* w0p = (const float4*)&wl[cc0*WS];
  const float4* w1p = (const float4*)&wl[cc1*WS];
  const float4* x0p = (const float4*)&xs[(tg     )*WS];
  const float4* x1p = (const float4*)&xs[(tg +  8)*WS];
  const float4* x2p = (const float4*)&xs[(tg + 16)*WS];
  const float4* x3p = (const float4*)&xs[(tg + 24)*WS];
  #pragma unroll 4
  for (int jc = 0; jc < DI/4; jc++){
    float4 w0 = w0p[jc], w1 = w1p[jc];
    float4 x0 = x0p[jc], x1 = x1p[jc], x2 = x2p[jc], x3 = x3p[jc];
    a0x = fmaf(w0.x,x0.x,fmaf(w0.y,x0.y,fmaf(w0.z,x0.z,fmaf(w0.w,x0.w,a0x))));
    a0y = fmaf(w0.x,x1.x,fmaf(w0.y,x1.y,fmaf(w0.z,x1.z,fmaf(w0.w,x1.w,a0y))));
    a0z = fmaf(w0.x,x2.x,fmaf(w0.y,x2.y,fmaf(w0.z,x2.z,fmaf(w0.w,x2.w,a0z))));
    a0w = fmaf(w0.x,x3.x,fmaf(w0.y,x3.y,fmaf(w0.z,x3.z,fmaf(w0.w,x3.w,a0w))));
    a1x = fmaf(w1.x,x0.x,fmaf(w1.y,x0.y,fmaf(w1.z,x0.z,fmaf(w1.w,x0.w,a1x))));
    a1y = fmaf(w1.x,x1.x,fmaf(w1.y,x1.y,fmaf(w1.z,x1.z,fmaf(w1.w,x1.w,a1y))));
    a1z = fmaf(w1.x,x2.x,fmaf(w1.y,x2.y,fmaf(w1.z,x2.z,fmaf(w1.w,x2.w,a1z))));
    a1w = fmaf(w1.x,x3.x,fmaf(w1.y,x3.y,fmaf(w1.z,x3.z,fmaf(w1.w,x3.w,a1w))));
  }
  float accs0[4] = {a0x,a0y,a0z,a0w};
  float accs1[4] = {a1x,a1y,a1z,a1w};
  #pragma unroll
  for (int i=0;i<4;i++){
    int t = t_base + tg + 8*i;
    size_t kt = (size_t)k*LL + t;
    {
      int cc = cc0; float v = accs0[i];
      if (cc < RK)            dts[kt*RKP + cc] = v;
      else if (cc < RK+NS)    Bb [kt*NS + (cc-RK)] = v;
      else                    Cb [kt*NS + (cc-RK-NS)] = v;
    }
    if (has2){
      int cc = ty + 32; float v = accs1[i];
      if (cc < RK+NS)         Bb [kt*NS + (cc-RK)] = v;
      else                    Cb [kt*NS + (cc-RK-NS)] = v;
    }
  }
}

// -------- K4a: single scan pass: local scan + C-dot y emit + SD store + (P,H) --------
template<int CHB>
__global__ void __launch_bounds__(256) k_scan1(
                      const float* __restrict__ xc,
                      const float* __restrict__ dts,
                      const float* __restrict__ Bbuf,
                      const float* __restrict__ Cbuf,
                      const float* __restrict__ A_logs,
                      const float* __restrict__ dtw,
                      const float* __restrict__ dtb,
                      float* __restrict__ Pb, float* __restrict__ Hb,
                      float* __restrict__ SDb,
                      float* __restrict__ yacc) {
  constexpr int CS = LL >> CHB;
  int b = blockIdx.x;             // ((k*3+dg3)<<CHB) | c
  int c = b & ((1<<CHB)-1);
  int kg = b >> CHB;
  int k = kg / 3, dg3 = kg - k*3;
  int tid = threadIdx.x;
  int dl = tid >> 2, nq = tid & 3;
  int d = dg3*64 + dl;
  int kd = k*DI + d;
  float4 Al = *(const float4*)&A_logs[kd*NS + nq*4];
  float A0 = -__expf(Al.x)*L2E, A1 = -__expf(Al.y)*L2E;
  float A2 = -__expf(Al.z)*L2E, A3 = -__expf(Al.w)*L2E;
  float bt = dtb[kd];
  float w0 = dtw[kd*RK+0], w1 = dtw[kd*RK+1], w2 = dtw[kd*RK+2];
  float w3 = dtw[kd*RK+3], w4 = dtw[kd*RK+4], w5 = dtw[kd*RK+5];
  const float* dr = dts + ((size_t)k*LL + c*CS)*RKP;
  const float4* bp = (const float4*)(Bbuf + ((size_t)k*LL + c*CS)*NS) + nq;
  const float4* cp = (const float4*)(Cbuf + ((size_t)k*LL + c*CS)*NS) + nq;
  float h0=0.f,h1=0.f,h2=0.f,h3=0.f, cumD=0.f;
  for (int s=0; s<CS; s++){
    int t = c*CS + s;
    float4 lo = *(const float4*)(dr + s*RKP);
    float4 hi = *(const float4*)(dr + s*RKP + 4);
    float v = bt;
    v = fmaf(w0, lo.x, v); v = fmaf(w1, lo.y, v); v = fmaf(w2, lo.z, v);
    v = fmaf(w3, lo.w, v); v = fmaf(w4, hi.x, v); v = fmaf(w5, hi.y, v);
    float sp = (v > 20.f) ? v : __logf(1.f + __expf(v));
    cumD += sp;
    int l = dir_map(k,t);
    float sx = sp * xc[l*DI + d];
    float4 bv = bp[s*4];
    float4 cv = cp[s*4];
    float a;
    a = exp2f(sp*A0); h0 = fmaf(a, h0, sx*bv.x);
    a = exp2f(sp*A1); h1 = fmaf(a, h1, sx*bv.y);
    a = exp2f(sp*A2); h2 = fmaf(a, h2, sx*bv.z);
    a = exp2f(sp*A3); h3 = fmaf(a, h3, sx*bv.w);
    float y = h0*cv.x + h1*cv.y + h2*cv.z + h3*cv.w;
    y += __shfl_xor(y, 1, 64);
    y += __shfl_xor(y, 2, 64);
    if (nq == 0){
      atomicAdd(&yacc[(size_t)l*DI + d], y);
      SDb[(size_t)(k*LL + t)*DI + d] = cumD;
    }
  }
  int base = c*NC + kd*NS + nq*4;
  // chunk decay product in closed form: prod exp2(A*sp) = exp2(A*cumD)
  *(float4*)&Pb[base] = make_float4(exp2f(A0*cumD), exp2f(A1*cumD),
                                    exp2f(A2*cumD), exp2f(A3*cumD));
  *(float4*)&Hb[base] = make_float4(h0,h1,h2,h3);
}

// -------- K4b: phase-2 combine, IN-PLACE: Hb[c] <- chunk-entry state --------
__global__ void __launch_bounds__(256) k_scan2(
                      const float* __restrict__ Pb, float* __restrict__ Hb,
                      int CHn) {
  int idx = blockIdx.x*256 + threadIdx.x;   // < 12288
  float h = 0.f;
  #pragma unroll 4
  for (int c=0;c<CHn;c++){
    float P = Pb[c*NC + idx];
    float Hc = Hb[c*NC + idx];
    Hb[c*NC + idx] = h;
    h = fmaf(P, h, Hc);
  }
}

// -------- K4c: parallel correction: y += C_t . (exp2(A2*SD_t) * h_entry) --------
template<int CHB>
__global__ void __launch_bounds__(192) k_corr(
                      const float* __restrict__ Cbuf,
                      const float* __restrict__ A_logs,
                      const float* __restrict__ Hb,     // entry states
                      const float* __restrict__ SDb,
                      float* __restrict__ yacc) {
  int b = blockIdx.x;              // KD*128: (k, 32-t tile)
  int k = b >> 7;
  int t0 = (b & 127) * 32;
  int c = t0 >> (12 - CHB);        // chunk containing this tile
  if (c == 0) return;              // entry state is zero -> no correction
  int d = threadIdx.x;             // 192
  int kd = k*DI + d;
  __shared__ float cs[32*NS];      // 2 KB: C for the 32 t's
  for (int i = d; i < 32*NS; i += 192)
    cs[i] = Cbuf[((size_t)k*LL + t0)*NS + i];
  float A2[16], he[16];
  {
    const float4* ap = (const float4*)&A_logs[kd*NS];
    const float4* hp = (const float4*)&Hb[c*NC + kd*NS];
    #pragma unroll
    for (int i=0;i<4;i++){
      float4 av = ap[i];
      A2[4*i+0] = -__expf(av.x)*L2E; A2[4*i+1] = -__expf(av.y)*L2E;
      A2[4*i+2] = -__expf(av.z)*L2E; A2[4*i+3] = -__expf(av.w)*L2E;
      *(float4*)&he[4*i] = hp[i];
    }
  }
  __syncthreads();
  for (int s=0; s<32; s++){
    int t = t0 + s;
    float SD = SDb[(size_t)(k*LL + t)*DI + d];
    float corr = 0.f;
    #pragma unroll
    for (int n=0;n<16;n++)
      corr = fmaf(cs[s*NS+n]*exp2f(A2[n]*SD), he[n], corr);
    atomicAdd(&yacc[(size_t)dir_map(k,t)*DI + d], corr);
  }
}

// -------- K5a: merge + x*sumD, LayerNorm, *silu(z) -> g --------
__global__ void k_ln(const float* __restrict__ yacc,
                     const float* __restrict__ xc,
                     const float* __restrict__ z,
                     const float* __restrict__ Ds,
                     const float* __restrict__ ln_g,
                     const float* __restrict__ ln_b,
                     float* __restrict__ g) {
  int l = blockIdx.x;
  int d = threadIdx.x; // 192
  float y = yacc[(size_t)l*DI + d];
  float dsum = Ds[0*DI+d] + Ds[1*DI+d] + Ds[2*DI+d] + Ds[3*DI+d];
  y = fmaf(xc[l*DI+d], dsum, y);
  float s1 = y, s2 = y*y;
  #pragma unroll
  for (int off=32; off; off>>=1){
    s1 += __shfl_xor(s1, off, 64);
    s2 += __shfl_xor(s2, off, 64);
  }
  __shared__ float red[6];
  int wave = d >> 6;
  if ((d & 63) == 0){ red[wave] = s1; red[3+wave] = s2; }
  __syncthreads();
  float sum = red[0]+red[1]+red[2];
  float sq  = red[3]+red[4]+red[5];
  float mu = sum * (1.f/192.f);
  float var = sq * (1.f/192.f) - mu*mu;
  float rstd = rsqrtf(var + 1e-5f);
  float yn = (y - mu) * rstd * ln_g[d] + ln_b[d];
  float zv = z[l*DI + d];
  g[(size_t)l*DI + d] = yn * (zv / (1.f + __expf(-zv)));
}

// -------- K5b: out_proj GEMM (4096x192)*(192x96)^T, 16-l tile, 8 acc/thread --------
__global__ void __launch_bounds__(192) k_oproj(const float* __restrict__ g,
                      const float* __restrict__ opw,
                      void* __restrict__ out,
                      const unsigned short* __restrict__ xh) {
  __shared__ float gs[OT*WS];      // 12.5 KB
  __shared__ int sflag;
  int tid = threadIdx.x;           // 192
  detect_bf16(xh, tid, &sflag);
  int l0 = blockIdx.x * OT;        // 256 blocks
  const float4* gsrc = (const float4*)(g + (size_t)l0*DI);
  for (int idx = tid; idx < OT*DI/4; idx += 192){
    int row = idx / 48, col = idx - row*48;
    float4 v = gsrc[idx];
    *(float4*)&gs[row*WS + col*4] = v;
  }
  __syncthreads();
  int half = tid / 96;             // 0/1 -> rows half*8..half*8+7
  int e = tid - half*96;
  int r0 = half*8;
  float acc[8];
  #pragma unroll
  for (int i=0;i<8;i++) acc[i] = 0.f;
  const float4* wrow = (const float4*)(opw + e*DI);
  #pragma unroll 4
  for (int jc = 0; jc < DI/4; jc++){
    float4 w = wrow[jc];
    #pragma unroll
    for (int i=0;i<8;i++){
      float4 gv = *(const float4*)&gs[(r0+i)*WS + jc*4];
      acc[i] = fmaf(w.x,gv.x,fmaf(w.y,gv.y,fmaf(w.z,gv.z,fmaf(w.w,gv.w,acc[i]))));
    }
  }
  int f = sflag;
  #pragma unroll
  for (int i=0;i<8;i++){
    int l = l0 + r0 + i;
    if (f) ((__hip_bfloat16*)out)[l*DM + e] = __float2bfloat16(acc[i]);
    else   ((float*)out)[l*DM + e] = acc[i];
  }
}

extern "C" void kernel_launch(void* const* d_in, const int* in_sizes, int n_in,
                              void* d_out, int out_size, void* d_ws, size_t ws_size,
                              hipStream_t stream) {
  float* ws = (float*)d_ws;
  float* cvt = ws + 16;
  const int off[13] = {0,393216,430080,431808,432000,461184,465792,466560,
                       478848,479616,479808,480000,498432};
  float* c[12];
  for (int i = 0; i < 12; i++) c[i] = cvt + off[i];

  float* big    = cvt + 498432;
  float* xx     = big;                       // 786432; dead after k_conv -> yacc
  float* z      = xx + (size_t)LL*DI;        // 786432
  float* xc     = z  + (size_t)LL*DI;        // 786432
  float* dts    = xc + (size_t)LL*DI;        // 131072 (RKP=8 padded)
  float* Bb     = dts + (size_t)KD*LL*RKP;   // 262144
  float* Cb     = Bb + (size_t)KD*LL*NS;     // 262144
  float* Pb     = Cb + (size_t)KD*LL*NS;     // CHn*NC
  // footprint(chBits=7): ~39.2 MB; ws_size measured 256 MiB
  size_t need128 = (size_t)(16 + 498432 + 3*786432 + 131072 + 2*262144
                            + 2*128*NC + (size_t)KD*LL*DI) * 4;
  int chBits = (ws_size >= need128) ? 7 : 6;
  int CHn = 1 << chBits;
  float* Hb   = Pb + (size_t)CHn*NC;
  float* SDb  = Hb + (size_t)CHn*NC;         // KD*LL*DI = 3145728
  float* yacc = xx;

  P12 ptrs;
  for (int i = 0; i < 12; i++) ptrs.p[i] = d_in[i];
  k_convert_all<<<(498432 + 255)/256, 256, 0, stream>>>(ptrs, cvt);

  k_inproj<<<LL/8, 384, 0, stream>>>(c[0], c[1], xx, z);
  k_conv<<<LL, DI, 0, stream>>>(xx, c[2], c[3], xc);
  k_proj<<<KD*(LL/PT), 256, 0, stream>>>(xc, c[4], dts, Bb, Cb, yacc);
  if (chBits == 7){
    k_scan1<7><<<KD*3*128, 256, 0, stream>>>(xc, dts, Bb, Cb, c[7], c[5], c[6], Pb, Hb, SDb, yacc);
    k_scan2<<<NC/256, 256, 0, stream>>>(Pb, Hb, 128);
    k_corr<7><<<KD*128, 192, 0, stream>>>(Cb, c[7], Hb, SDb, yacc);
  } else {
    k_scan1<6><<<KD*3*64, 256, 0, stream>>>(xc, dts, Bb, Cb, c[7], c[5], c[6], Pb, Hb, SDb, yacc);
    k_scan2<<<NC/256, 256, 0, stream>>>(Pb, Hb, 64);
    k_corr<6><<<KD*128, 192, 0, stream>>>(Cb, c[7], Hb, SDb, yacc);
  }
  k_ln<<<LL, DI, 0, stream>>>(yacc, xc, z, c[8], c[9], c[10], Hb);
  k_oproj<<<LL/OT, 192, 0, stream>>>(Hb, c[11], d_out, (const unsigned short*)d_in[0]);
}

// Round 13
// 207.792 us; speedup vs baseline: 1.0433x; 1.0433x over previous
//
#include <hip/hip_runtime.h>
#include <hip/hip_bf16.h>

#define LL 4096
#define DM 96
#define DI 192
#define NS 16
#define RK 6
#define RKP 8              // padded stride for dt coeffs (16B alignment)
#define KD 4
#define CPROJ 38
#define NC (KD*DI*NS)      // 12288 independent chains
#define PT 32              // t-tile for k_proj
#define WS 196             // LDS row stride (4*odd -> quad-bank spread)
#define OT 16              // l-tile for k_oproj
#define L2E 1.44269504f

__device__ __forceinline__ float b2f(__hip_bfloat16 v){ return __bfloat162float(v); }

// inline dtype detect: 64 lanes sample even halfwords of x; bf16 data has sane exponents
__device__ __forceinline__ int detect_bf16(const unsigned short* __restrict__ xh, int tid, int* sflag){
  if (tid < 64){
    unsigned short u = xh[2*tid];
    int e = (u >> 7) & 0xFF;
    int sane = (e >= 107 && e <= 131) ? 1 : 0;
    unsigned long long m = __ballot(sane);
    if (tid == 0) *sflag = (__popcll(m) >= 32) ? 1 : 0;
  }
  return 0;
}

// -------- K0: convert ALL 12 tensors to fp32 in one launch (self-detecting) --------
struct P12 { const void* p[12]; };
__global__ void k_convert_all(P12 ptrs, float* __restrict__ dst) {
  const int off[13] = {0,393216,430080,431808,432000,461184,465792,466560,
                       478848,479616,479808,480000,498432};
  __shared__ int sflag;
  detect_bf16((const unsigned short*)ptrs.p[0], threadIdx.x, &sflag);
  __syncthreads();
  int f = sflag;
  int i = blockIdx.x * 256 + threadIdx.x;
  if (i >= 498432) return;
  int j = 0;
  #pragma unroll
  for (int s = 1; s < 12; s++) if (i >= off[s]) j = s;
  int e = i - off[j];
  if (f) dst[i] = b2f(((const __hip_bfloat16*)ptrs.p[j])[e]);
  else   dst[i] = ((const float*)ptrs.p[j])[e];
}

// -------- K1: in_proj GEMM --------
__global__ void k_inproj(const float* __restrict__ x,
                         const float* __restrict__ w,
                         float* __restrict__ xx, float* __restrict__ z) {
  __shared__ float xr[8*DM];
  int l0 = blockIdx.x * 8;
  int tid = threadIdx.x; // 384
  for (int i = tid; i < 8*DM; i += 384) xr[i] = x[l0*DM + i];
  __syncthreads();
  int e = tid;
  float acc[8];
  #pragma unroll
  for (int i=0;i<8;i++) acc[i]=0.f;
  const float* wr = w + e*DM;
  for (int c=0;c<DM;c++){
    float wv = wr[c];
    #pragma unroll
    for (int i=0;i<8;i++) acc[i] = fmaf(wv, xr[i*DM+c], acc[i]);
  }
  if (e < DI) {
    #pragma unroll
    for (int i=0;i<8;i++) xx[(l0+i)*DI + e] = acc[i];
  } else {
    int e2 = e - DI;
    #pragma unroll
    for (int i=0;i<8;i++) z[(l0+i)*DI + e2] = acc[i];
  }
}

// -------- K2: depthwise 3x3 conv + bias + SiLU; writes xc AND transposed xct --------
__global__ void k_conv(const float* __restrict__ xx,
                       const float* __restrict__ cw,
                       const float* __restrict__ cb,
                       float* __restrict__ xc,
                       float* __restrict__ xct) {
  int l = blockIdx.x;
  int d = threadIdx.x; // 192
  int h = l >> 6, w = l & 63;
  float acc = cb[d];
  #pragma unroll
  for (int ki=0; ki<3; ki++){
    int hh = h + ki - 1;
    if ((unsigned)hh >= 64u) continue;
    #pragma unroll
    for (int kj=0;kj<3;kj++){
      int wj = w + kj - 1;
      if ((unsigned)wj >= 64u) continue;
      acc = fmaf(cw[d*9 + ki*3 + kj], xx[(hh*64+wj)*DI + d], acc);
    }
  }
  float v = acc / (1.f + __expf(-acc));
  xc[l*DI + d] = v;
  xct[(((w<<6)|h))*DI + d] = v;
}

__device__ __forceinline__ int dir_map(int k, int t){
  if (k==0) return t;
  if (k==1) return ((t&63)<<6) | (t>>6);
  if (k==2) return 4095 - t;
  int u = 4095 - t; return ((u&63)<<6) | (u>>6);
}

// -------- K3: x_dbl projection as register-tiled LDS GEMM; k<2 blocks zero yacc bufs --------
__global__ void __launch_bounds__(256) k_proj(const float* __restrict__ xc,
                       const float* __restrict__ xpw,
                       float* __restrict__ dts,
                       float* __restrict__ Bb, float* __restrict__ Cb,
                       float* __restrict__ yacc_hw, float* __restrict__ yacc_wh) {
  __shared__ float wl[CPROJ*WS];   // 29.8 KB
  __shared__ float xs[PT*WS];      // 25.1 KB
  int b = blockIdx.x;              // KD * 128
  int k = b >> 7;
  int t_base = (b & 127) * PT;
  int tid = threadIdx.x;
  if (k < 2){                      // zero yacc slice [t_base*DI, (t_base+PT)*DI)
    float4* yz = (float4*)((k==0 ? yacc_hw : yacc_wh) + (size_t)t_base*DI);
    for (int idx = tid; idx < PT*DI/4; idx += 256)
      yz[idx] = make_float4(0.f,0.f,0.f,0.f);
  }
  for (int idx = tid; idx < CPROJ*DI; idx += 256){
    int cc = idx / DI, j = idx - cc*DI;
    wl[cc*WS + j] = xpw[(k*CPROJ + cc)*DI + j];
  }
  for (int idx = tid; idx < PT*DI; idx += 256){
    int tt = idx / DI, j = idx - tt*DI;
    xs[tt*WS + j] = xc[dir_map(k, t_base + tt)*DI + j];
  }
  __syncthreads();
  int tg = tid & 7;        // t-group: cols {tg, tg+8, tg+16, tg+24}
  int ty = tid >> 3;       // 0..31: rows {ty, ty+32 if <38}
  int cc0 = ty;
  int has2 = (ty + 32 < CPROJ);
  int cc1 = has2 ? (ty + 32) : ty;
  float a0x=0.f,a0y=0.f,a0z=0.f,a0w=0.f;
  float a1x=0.f,a1y=0.f,a1z=0.f,a1w=0.f;
  const float4* w0p = (const float4*)&wl[cc0*WS];
  const float4* w1p = (const float4*)&wl[cc1*WS];
  const float4* x0p = (const float4*)&xs[(tg     )*WS];
  const float4* x1p = (const float4*)&xs[(tg +  8)*WS];
  const float4* x2p = (const float4*)&xs[(tg + 16)*WS];
  const float4* x3p = (const float4*)&xs[(tg + 24)*WS];
  #pragma unroll 4
  for (int jc = 0; jc < DI/4; jc++){
    float4 w0 = w0p[jc], w1 = w1p[jc];
    float4 x0 = x0p[jc], x1 = x1p[jc], x2 = x2p[jc], x3 = x3p[jc];
    a0x = fmaf(w0.x,x0.x,fmaf(w0.y,x0.y,fmaf(w0.z,x0.z,fmaf(w0.w,x0.w,a0x))));
    a0y = fmaf(w0.x,x1.x,fmaf(w0.y,x1.y,fmaf(w0.z,x1.z,fmaf(w0.w,x1.w,a0y))));
    a0z = fmaf(w0.x,x2.x,fmaf(w0.y,x2.y,fmaf(w0.z,x2.z,fmaf(w0.w,x2.w,a0z))));
    a0w = fmaf(w0.x,x3.x,fmaf(w0.y,x3.y,fmaf(w0.z,x3.z,fmaf(w0.w,x3.w,a0w))));
    a1x = fmaf(w1.x,x0.x,fmaf(w1.y,x0.y,fmaf(w1.z,x0.z,fmaf(w1.w,x0.w,a1x))));
    a1y = fmaf(w1.x,x1.x,fmaf(w1.y,x1.y,fmaf(w1.z,x1.z,fmaf(w1.w,x1.w,a1y))));
    a1z = fmaf(w1.x,x2.x,fmaf(w1.y,x2.y,fmaf(w1.z,x2.z,fmaf(w1.w,x2.w,a1z))));
    a1w = fmaf(w1.x,x3.x,fmaf(w1.y,x3.y,fmaf(w1.z,x3.z,fmaf(w1.w,x3.w,a1w))));
  }
  float accs0[4] = {a0x,a0y,a0z,a0w};
  float accs1[4] = {a1x,a1y,a1z,a1w};
  #pragma unroll
  for (int i=0;i<4;i++){
    int t = t_base + tg + 8*i;
    size_t kt = (size_t)k*LL + t;
    {
      int cc = cc0; float v = accs0[i];
      if (cc < RK)            dts[kt*RKP + cc] = v;
      else if (cc < RK+NS)    Bb [kt*NS + (cc-RK)] = v;
      else                    Cb [kt*NS + (cc-RK-NS)] = v;
    }
    if (has2){
      int cc = ty + 32; float v = accs1[i];
      if (cc < RK+NS)         Bb [kt*NS + (cc-RK)] = v;
      else                    Cb [kt*NS + (cc-RK-NS)] = v;
    }
  }
}

// -------- K4a: single scan pass, fully affine addressing --------
template<int CHB>
__global__ void __launch_bounds__(256) k_scan1(
                      const float* __restrict__ xc_hw,
                      const float* __restrict__ xc_wh,
                      const float* __restrict__ dts,
                      const float* __restrict__ Bbuf,
                      const float* __restrict__ Cbuf,
                      const float* __restrict__ A_logs,
                      const float* __restrict__ dtw,
                      const float* __restrict__ dtb,
                      float* __restrict__ Pb, float* __restrict__ Hb,
                      float* __restrict__ SDb,
                      float* __restrict__ yacc_hw, float* __restrict__ yacc_wh) {
  constexpr int CS = LL >> CHB;
  int b = blockIdx.x;             // ((k*3+dg3)<<CHB) | c
  int c = b & ((1<<CHB)-1);
  int kg = b >> CHB;
  int k = kg / 3, dg3 = kg - k*3;
  int tid = threadIdx.x;
  int dl = tid >> 2, nq = tid & 3;
  int d = dg3*64 + dl;
  int kd = k*DI + d;
  float4 Al = *(const float4*)&A_logs[kd*NS + nq*4];
  float A0 = -__expf(Al.x)*L2E, A1 = -__expf(Al.y)*L2E;
  float A2 = -__expf(Al.z)*L2E, A3 = -__expf(Al.w)*L2E;
  float bt = dtb[kd];
  float w0 = dtw[kd*RK+0], w1 = dtw[kd*RK+1], w2 = dtw[kd*RK+2];
  float w3 = dtw[kd*RK+3], w4 = dtw[kd*RK+4], w5 = dtw[kd*RK+5];
  const float* dr = dts + ((size_t)k*LL + c*CS)*RKP;
  const float4* bp = (const float4*)(Bbuf + ((size_t)k*LL + c*CS)*NS) + nq;
  const float4* cp = (const float4*)(Cbuf + ((size_t)k*LL + c*CS)*NS) + nq;
  const float* xbase = (k & 1) ? xc_wh : xc_hw;
  float* ybase = (k & 1) ? yacc_wh : yacc_hw;
  int l0 = (k < 2) ? (c*CS) : (4095 - c*CS);
  int lstep = (k < 2) ? DI : -DI;
  const float* xp = xbase + (size_t)l0*DI + d;
  float* yp = ybase + (size_t)l0*DI + d;
  float* sdp = SDb + ((size_t)k*LL + c*CS)*DI + d;
  float h0=0.f,h1=0.f,h2=0.f,h3=0.f, cumD=0.f;
  #pragma unroll
  for (int s=0; s<CS; s++){
    float4 lo = *(const float4*)(dr + s*RKP);
    float4 hi = *(const float4*)(dr + s*RKP + 4);
    float v = bt;
    v = fmaf(w0, lo.x, v); v = fmaf(w1, lo.y, v); v = fmaf(w2, lo.z, v);
    v = fmaf(w3, lo.w, v); v = fmaf(w4, hi.x, v); v = fmaf(w5, hi.y, v);
    float sp = (v > 20.f) ? v : __logf(1.f + __expf(v));
    cumD += sp;
    float sx = sp * xp[(ptrdiff_t)s*lstep];
    float4 bv = bp[s*4];
    float4 cv = cp[s*4];
    float a;
    a = exp2f(sp*A0); h0 = fmaf(a, h0, sx*bv.x);
    a = exp2f(sp*A1); h1 = fmaf(a, h1, sx*bv.y);
    a = exp2f(sp*A2); h2 = fmaf(a, h2, sx*bv.z);
    a = exp2f(sp*A3); h3 = fmaf(a, h3, sx*bv.w);
    float y = h0*cv.x + h1*cv.y + h2*cv.z + h3*cv.w;
    y += __shfl_xor(y, 1, 64);
    y += __shfl_xor(y, 2, 64);
    if (nq == 0){
      atomicAdd(&yp[(ptrdiff_t)s*lstep], y);
      sdp[s*DI] = cumD;
    }
  }
  int base = c*NC + kd*NS + nq*4;
  *(float4*)&Pb[base] = make_float4(exp2f(A0*cumD), exp2f(A1*cumD),
                                    exp2f(A2*cumD), exp2f(A3*cumD));
  *(float4*)&Hb[base] = make_float4(h0,h1,h2,h3);
}

// -------- K4b: phase-2 combine, IN-PLACE: Hb[c] <- chunk-entry state --------
template<int CHB>
__global__ void __launch_bounds__(256) k_scan2(
                      const float* __restrict__ Pb, float* __restrict__ Hb) {
  constexpr int CH = 1 << CHB;
  int idx = blockIdx.x*256 + threadIdx.x;   // < 12288
  float h = 0.f;
  #pragma unroll 8
  for (int c=0;c<CH;c++){
    float P = Pb[c*NC + idx];
    float Hc = Hb[c*NC + idx];
    Hb[c*NC + idx] = h;
    h = fmaf(P, h, Hc);
  }
}

// -------- K4c: parallel correction, one block per (k,chunk): y += C.(exp2(A*SD)*h_entry) --------
template<int CHB>
__global__ void __launch_bounds__(192) k_corr(
                      const float* __restrict__ Cbuf,
                      const float* __restrict__ A_logs,
                      const float* __restrict__ Hb,     // entry states
                      const float* __restrict__ SDb,
                      float* __restrict__ yacc_hw, float* __restrict__ yacc_wh) {
  constexpr int CS = LL >> CHB;
  int b = blockIdx.x;              // KD << CHB
  int k = b >> CHB;
  int c = b & ((1<<CHB)-1);
  if (c == 0) return;              // entry state is zero -> no correction
  int t0 = c*CS;
  int d = threadIdx.x;             // 192
  int kd = k*DI + d;
  __shared__ float cs[CS*NS];
  for (int i = d; i < CS*NS; i += 192)
    cs[i] = Cbuf[((size_t)k*LL + t0)*NS + i];
  float A2[16], he[16];
  {
    const float4* ap = (const float4*)&A_logs[kd*NS];
    const float4* hp = (const float4*)&Hb[c*NC + kd*NS];
    #pragma unroll
    for (int i=0;i<4;i++){
      float4 av = ap[i];
      A2[4*i+0] = -__expf(av.x)*L2E; A2[4*i+1] = -__expf(av.y)*L2E;
      A2[4*i+2] = -__expf(av.z)*L2E; A2[4*i+3] = -__expf(av.w)*L2E;
      *(float4*)&he[4*i] = hp[i];
    }
  }
  __syncthreads();
  float* ybase = (k & 1) ? yacc_wh : yacc_hw;
  int l0 = (k < 2) ? t0 : (4095 - t0);
  int lstep = (k < 2) ? DI : -DI;
  float* yp = ybase + (size_t)l0*DI + d;
  const float* sdp = SDb + ((size_t)k*LL + t0)*DI + d;
  #pragma unroll 4
  for (int s=0; s<CS; s++){
    float SD = sdp[s*DI];
    float corr = 0.f;
    #pragma unroll
    for (int n=0;n<16;n++)
      corr = fmaf(cs[s*NS+n]*exp2f(A2[n]*SD), he[n], corr);
    atomicAdd(&yp[(ptrdiff_t)s*lstep], corr);
  }
}

// -------- K5a: merge hw+wh + x*sumD, LayerNorm, *silu(z) -> g --------
__global__ void k_ln(const float* __restrict__ yacc_hw,
                     const float* __restrict__ yacc_wh,
                     const float* __restrict__ xc,
                     const float* __restrict__ z,
                     const float* __restrict__ Ds,
                     const float* __restrict__ ln_g,
                     const float* __restrict__ ln_b,
                     float* __restrict__ g) {
  int l = blockIdx.x;
  int d = threadIdx.x; // 192
  int lt = ((l & 63) << 6) | (l >> 6);
  float y = yacc_hw[(size_t)l*DI + d] + yacc_wh[(size_t)lt*DI + d];
  float dsum = Ds[0*DI+d] + Ds[1*DI+d] + Ds[2*DI+d] + Ds[3*DI+d];
  y = fmaf(xc[l*DI+d], dsum, y);
  float s1 = y, s2 = y*y;
  #pragma unroll
  for (int off=32; off; off>>=1){
    s1 += __shfl_xor(s1, off, 64);
    s2 += __shfl_xor(s2, off, 64);
  }
  __shared__ float red[6];
  int wave = d >> 6;
  if ((d & 63) == 0){ red[wave] = s1; red[3+wave] = s2; }
  __syncthreads();
  float sum = red[0]+red[1]+red[2];
  float sq  = red[3]+red[4]+red[5];
  float mu = sum * (1.f/192.f);
  float var = sq * (1.f/192.f) - mu*mu;
  float rstd = rsqrtf(var + 1e-5f);
  float yn = (y - mu) * rstd * ln_g[d] + ln_b[d];
  float zv = z[l*DI + d];
  g[(size_t)l*DI + d] = yn * (zv / (1.f + __expf(-zv)));
}

// -------- K5b: out_proj GEMM (4096x192)*(192x96)^T, 16-l tile, 8 acc/thread --------
__global__ void __launch_bounds__(192) k_oproj(const float* __restrict__ g,
                      const float* __restrict__ opw,
                      void* __restrict__ out,
                      const unsigned short* __restrict__ xh) {
  __shared__ float gs[OT*WS];      // 12.5 KB
  __shared__ int sflag;
  int tid = threadIdx.x;           // 192
  detect_bf16(xh, tid, &sflag);
  int l0 = blockIdx.x * OT;        // 256 blocks
  const float4* gsrc = (const float4*)(g + (size_t)l0*DI);
  for (int idx = tid; idx < OT*DI/4; idx += 192){
    int row = idx / 48, col = idx - row*48;
    float4 v = gsrc[idx];
    *(float4*)&gs[row*WS + col*4] = v;
  }
  __syncthreads();
  int half = tid / 96;             // 0/1 -> rows half*8..half*8+7
  int e = tid - half*96;
  int r0 = half*8;
  float acc[8];
  #pragma unroll
  for (int i=0;i<8;i++) acc[i] = 0.f;
  const float4* wrow = (const float4*)(opw + e*DI);
  #pragma unroll 4
  for (int jc = 0; jc < DI/4; jc++){
    float4 w = wrow[jc];
    #pragma unroll
    for (int i=0;i<8;i++){
      float4 gv = *(const float4*)&gs[(r0+i)*WS + jc*4];
      acc[i] = fmaf(w.x,gv.x,fmaf(w.y,gv.y,fmaf(w.z,gv.z,fmaf(w.w,gv.w,acc[i]))));
    }
  }
  int f = sflag;
  #pragma unroll
  for (int i=0;i<8;i++){
    int l = l0 + r0 + i;
    if (f) ((__hip_bfloat16*)out)[l*DM + e] = __float2bfloat16(acc[i]);
    else   ((float*)out)[l*DM + e] = acc[i];
  }
}

extern "C" void kernel_launch(void* const* d_in, const int* in_sizes, int n_in,
                              void* d_out, int out_size, void* d_ws, size_t ws_size,
                              hipStream_t stream) {
  float* ws = (float*)d_ws;
  float* cvt = ws + 16;
  const int off[13] = {0,393216,430080,431808,432000,461184,465792,466560,
                       478848,479616,479808,480000,498432};
  float* c[12];
  for (int i = 0; i < 12; i++) c[i] = cvt + off[i];

  float* big    = cvt + 498432;
  float* xx     = big;                       // 786432; dead after k_conv -> yacc_hw
  float* z      = xx + (size_t)LL*DI;        // 786432
  float* xc     = z  + (size_t)LL*DI;        // 786432
  float* xct    = xc + (size_t)LL*DI;        // 786432
  float* dts    = xct + (size_t)LL*DI;       // 131072 (RKP=8 padded)
  float* Bb     = dts + (size_t)KD*LL*RKP;   // 262144
  float* Cb     = Bb + (size_t)KD*LL*NS;     // 262144
  float* Pb     = Cb + (size_t)KD*LL*NS;     // CHn*NC
  // footprint(CHB=8): ~58.1 MB; (CHB=6): ~39.2 MB. ws_size measured 256 MiB.
  size_t need256 = (size_t)(16 + 498432 + 4*786432 + 131072 + 2*262144
                            + 2*256*NC + (size_t)KD*LL*DI + 786432) * 4;
  int chBits = (ws_size >= need256) ? 8 : 6;
  int CHn = 1 << chBits;
  float* Hb      = Pb + (size_t)CHn*NC;
  float* SDb     = Hb + (size_t)CHn*NC;      // KD*LL*DI = 3145728
  float* yacc_wh = SDb + (size_t)KD*LL*DI;   // 786432
  float* yacc_hw = xx;                       // alias

  P12 ptrs;
  for (int i = 0; i < 12; i++) ptrs.p[i] = d_in[i];
  k_convert_all<<<(498432 + 255)/256, 256, 0, stream>>>(ptrs, cvt);

  k_inproj<<<LL/8, 384, 0, stream>>>(c[0], c[1], xx, z);
  k_conv<<<LL, DI, 0, stream>>>(xx, c[2], c[3], xc, xct);
  k_proj<<<KD*(LL/PT), 256, 0, stream>>>(xc, c[4], dts, Bb, Cb, yacc_hw, yacc_wh);
  if (chBits == 8){
    k_scan1<8><<<KD*3*256, 256, 0, stream>>>(xc, xct, dts, Bb, Cb, c[7], c[5], c[6],
                                             Pb, Hb, SDb, yacc_hw, yacc_wh);
    k_scan2<8><<<NC/256, 256, 0, stream>>>(Pb, Hb);
    k_corr<8><<<KD*256, 192, 0, stream>>>(Cb, c[7], Hb, SDb, yacc_hw, yacc_wh);
  } else {
    k_scan1<6><<<KD*3*64, 256, 0, stream>>>(xc, xct, dts, Bb, Cb, c[7], c[5], c[6],
                                            Pb, Hb, SDb, yacc_hw, yacc_wh);
    k_scan2<6><<<NC/256, 256, 0, stream>>>(Pb, Hb);
    k_corr<6><<<KD*64, 192, 0, stream>>>(Cb, c[7], Hb, SDb, yacc_hw, yacc_wh);
  }
  k_ln<<<LL, DI, 0, stream>>>(yacc_hw, yacc_wh, xc, z, c[8], c[9], c[10], Hb);
  k_oproj<<<LL/OT, 192, 0, stream>>>(Hb, c[11], d_out, (const unsigned short*)d_in[0]);
}